// Round 15
// baseline (580.728 us; speedup 1.0000x reference)
//
#include <hip/hip_runtime.h>
#include <stdint.h>

typedef unsigned int uint;
typedef unsigned short ushort;
typedef __attribute__((ext_vector_type(4))) float  f32x4;
typedef __attribute__((ext_vector_type(8))) __bf16 bf16x8;

#define SCALE 0.125f   // 1/sqrt(64)

__device__ __forceinline__ ushort f2bf(float f) {
  uint u = __builtin_bit_cast(uint, f);
  u += 0x7FFFu + ((u >> 16) & 1u);
  return (ushort)(u >> 16);
}
__device__ __forceinline__ uint pack2bf(float a, float b) {
  return (uint)f2bf(a) | ((uint)f2bf(b) << 16);
}
__device__ __forceinline__ float bflo(uint u) { return __builtin_bit_cast(float, u << 16); }
__device__ __forceinline__ float bfhi(uint u) { return __builtin_bit_cast(float, u & 0xFFFF0000u); }

__device__ __forceinline__ void gload_lds16(const void* g, void* l) {
  __builtin_amdgcn_global_load_lds((const __attribute__((address_space(1))) void*)g,
                                   (__attribute__((address_space(3))) void*)l, 16, 0, 0);
}

__device__ __forceinline__ void unpack8(uint4 u, float s, float* x) {
  x[0]=bflo(u.x)*s; x[1]=bfhi(u.x)*s; x[2]=bflo(u.y)*s; x[3]=bfhi(u.y)*s;
  x[4]=bflo(u.z)*s; x[5]=bfhi(u.z)*s; x[6]=bflo(u.w)*s; x[7]=bfhi(u.w)*s;
}

// ---------------- fused conversions: x->bf16, Wqkv->transposed bf16, S + counters zero ----------

__global__ __launch_bounds__(256) void cvt_all_kernel(
    const float4* __restrict__ x, uint2* __restrict__ xb,
    const float* __restrict__ Wq, const float* __restrict__ Wk, const float* __restrict__ Wv,
    ushort* __restrict__ WT, float4* __restrict__ S4, int* __restrict__ counters) {
  __shared__ float tile[32][33];
  int bx = blockIdx.x;
  if (bx < 2048) {
    int i = bx * 256 + threadIdx.x;   // 524288 threads
    #pragma unroll
    for (int k = 0; k < 8; ++k) {
      int idx = i + k * 524288;       // total 4194304 float4s
      float4 f = x[idx];
      xb[idx] = make_uint2(pack2bf(f.x, f.y), pack2bf(f.z, f.w));
    }
  } else if (bx < 5120) {
    int lin = bx - 2048;              // 0..3071
    int mat = lin >> 10;
    int rem = lin & 1023;
    int cb = rem & 31, rb = rem >> 5;
    const float* W = (mat == 0) ? Wq : (mat == 1) ? Wk : Wv;
    int tx = threadIdx.x & 31, ty = threadIdx.x >> 5;
    int c0 = cb * 32, r0 = rb * 32;
    #pragma unroll
    for (int i = 0; i < 4; ++i)
      tile[ty + i*8][tx] = W[(size_t)(r0 + ty + i*8) * 1024 + c0 + tx];
    __syncthreads();
    #pragma unroll
    for (int i = 0; i < 4; ++i)
      WT[(size_t)(mat*1024 + c0 + ty + i*8) * 1024 + r0 + tx] = f2bf(tile[tx][ty + i*8]);
  } else {
    // zero S: 64*4096 floats = 65536 float4s; 32 blocks x 256 threads x 8
    int base = ((bx - 5120) * 256 + threadIdx.x) * 8;
    const float4 z = {0.f, 0.f, 0.f, 0.f};
    #pragma unroll
    for (int j = 0; j < 8; ++j) S4[base + j] = z;
    if (bx == 5120 && threadIdx.x < 64) counters[threadIdx.x] = 0;
  }
}

// ---------------- GEMM1: QKV = xb @ WqkvT^T, fused q-softmax epilogue ----------------
// 128x128 tile, m97 structure. Grid dim3(128, 24): x=m-tile (XCD partition axis).
// n0<1024: q path -> softmax(acc+bq) -> qs (bf16). Else: k/v -> QKV + bias (bf16).

__global__ __launch_bounds__(256, 2) void gemm1_qkv(
    const ushort* __restrict__ A, const ushort* __restrict__ B,
    ushort* __restrict__ QKV, ushort* __restrict__ qs,
    const float* __restrict__ bq, const float* __restrict__ bk, const float* __restrict__ bv) {
  __shared__ ushort As[128 * 64];
  __shared__ ushort Bs[128 * 64];
  const int K = 1024;
  const int t = threadIdx.x;
  const int w = t >> 6, l = t & 63;
  const int wr = w >> 1, wc = w & 1;
  const int m0 = blockIdx.x * 128;
  const int n0 = blockIdx.y * 128;
  const ushort* Ap = A + (size_t)m0 * K;
  const ushort* Bp = B + (size_t)n0 * K;

  f32x4 acc[4][4];
  const f32x4 zf = {0.f, 0.f, 0.f, 0.f};
  #pragma unroll
  for (int i = 0; i < 4; ++i)
    #pragma unroll
    for (int j = 0; j < 4; ++j) acc[i][j] = zf;

  const int lr = l & 15, lg = l >> 4;

  for (int kt = 0; kt < K; kt += 64) {
    #pragma unroll
    for (int i = 0; i < 4; ++i) {
      int gb = w * 64 + i * 256;
      int g  = gb + l;
      int row = g >> 3, c16 = g & 7;
      gload_lds16(Ap + (size_t)row * K + kt + c16 * 8, (void*)(As + gb * 8));
      gload_lds16(Bp + (size_t)row * K + kt + c16 * 8, (void*)(Bs + gb * 8));
    }
    __syncthreads();
    #pragma unroll
    for (int kk = 0; kk < 64; kk += 32) {
      bf16x8 a[4], b[4];
      #pragma unroll
      for (int m = 0; m < 4; ++m)
        a[m] = *(const bf16x8*)(As + (wr*64 + m*16 + lr) * 64 + kk + lg * 8);
      #pragma unroll
      for (int n = 0; n < 4; ++n)
        b[n] = *(const bf16x8*)(Bs + (wc*64 + n*16 + lr) * 64 + kk + lg * 8);
      #pragma unroll
      for (int m = 0; m < 4; ++m)
        #pragma unroll
        for (int n = 0; n < 4; ++n)
          acc[m][n] = __builtin_amdgcn_mfma_f32_16x16x32_bf16(a[m], b[n], acc[m][n], 0, 0, 0);
    }
    __syncthreads();
  }

  // C/D mapping: col=lane&15, row=(lane>>4)*4+j (m89)
  if (n0 < 1024) {
    // q path: softmax over the wave's 64-col head chunk (4 regs x 16 lr lanes)
    const int cb = n0 + wc * 64;
    float bvv[4];
    #pragma unroll
    for (int n = 0; n < 4; ++n) bvv[n] = bq[cb + n*16 + lr];
    #pragma unroll
    for (int m = 0; m < 4; ++m) {
      #pragma unroll
      for (int j = 0; j < 4; ++j) {
        int row = m0 + wr*64 + m*16 + lg*4 + j;
        float v[4];
        float s = 0.f;
        #pragma unroll
        for (int n = 0; n < 4; ++n) {
          v[n] = __expf((acc[m][n][j] + bvv[n]) * SCALE);
          s += v[n];
        }
        s += __shfl_xor(s, 1);
        s += __shfl_xor(s, 2);
        s += __shfl_xor(s, 4);
        s += __shfl_xor(s, 8);
        float inv = 1.f / s;
        #pragma unroll
        for (int n = 0; n < 4; ++n)
          qs[(size_t)row * 1024 + cb + n*16 + lr] = f2bf(v[n] * inv);
      }
    }
  } else {
    const float* bp = (n0 < 2048) ? bk : bv;
    #pragma unroll
    for (int n = 0; n < 4; ++n) {
      int col = n0 + wc*64 + n*16 + lr;
      float bvv = bp[col & 1023];
      #pragma unroll
      for (int m = 0; m < 4; ++m) {
        #pragma unroll
        for (int j = 0; j < 4; ++j) {
          int row = m0 + wr*64 + m*16 + lg*4 + j;
          QKV[(size_t)row * 3072 + col] = f2bf(acc[m][n][j] + bvv);
        }
      }
    }
  }
}

// ---------------- GEMM2: out = qs @ W2T^T + bo (f32 out) ----------------

__global__ __launch_bounds__(256, 2) void gemm2_out(
    const ushort* __restrict__ A, const ushort* __restrict__ B, float* __restrict__ C,
    const float* __restrict__ bo) {
  __shared__ ushort As[128 * 64];
  __shared__ ushort Bs[128 * 64];
  const int K = 1024;
  const int t = threadIdx.x;
  const int w = t >> 6, l = t & 63;
  const int wr = w >> 1, wc = w & 1;
  const int m0 = blockIdx.x * 128;
  const int n0 = blockIdx.y * 128;
  const ushort* Ap = A + (size_t)m0 * K;
  const ushort* Bp = B + (size_t)(m0 >> 12) * (1024 * 1024) + (size_t)n0 * K;

  f32x4 acc[4][4];
  const f32x4 zf = {0.f, 0.f, 0.f, 0.f};
  #pragma unroll
  for (int i = 0; i < 4; ++i)
    #pragma unroll
    for (int j = 0; j < 4; ++j) acc[i][j] = zf;

  const int lr = l & 15, lg = l >> 4;

  for (int kt = 0; kt < K; kt += 64) {
    #pragma unroll
    for (int i = 0; i < 4; ++i) {
      int gb = w * 64 + i * 256;
      int g  = gb + l;
      int row = g >> 3, c16 = g & 7;
      gload_lds16(Ap + (size_t)row * K + kt + c16 * 8, (void*)(As + gb * 8));
      gload_lds16(Bp + (size_t)row * K + kt + c16 * 8, (void*)(Bs + gb * 8));
    }
    __syncthreads();
    #pragma unroll
    for (int kk = 0; kk < 64; kk += 32) {
      bf16x8 a[4], b[4];
      #pragma unroll
      for (int m = 0; m < 4; ++m)
        a[m] = *(const bf16x8*)(As + (wr*64 + m*16 + lr) * 64 + kk + lg * 8);
      #pragma unroll
      for (int n = 0; n < 4; ++n)
        b[n] = *(const bf16x8*)(Bs + (wc*64 + n*16 + lr) * 64 + kk + lg * 8);
      #pragma unroll
      for (int m = 0; m < 4; ++m)
        #pragma unroll
        for (int n = 0; n < 4; ++n)
          acc[m][n] = __builtin_amdgcn_mfma_f32_16x16x32_bf16(a[m], b[n], acc[m][n], 0, 0, 0);
    }
    __syncthreads();
  }

  #pragma unroll
  for (int n = 0; n < 4; ++n) {
    int col = n0 + wc*64 + n*16 + lr;
    float bvv = bo[col];
    #pragma unroll
    for (int m = 0; m < 4; ++m) {
      #pragma unroll
      for (int j = 0; j < 4; ++j) {
        int row = m0 + wr*64 + m*16 + lg*4 + j;
        C[(size_t)row * 1024 + col] = acc[m][n][j] + bvv;
      }
    }
  }
}

// ---------------- fused: softmax(k)+softmax(mk), S += w^T v, last-finisher builds W2T ----------
// 1024 blocks = (b,h) x 16 chunks of 256 rows; each block does 2 sequential 128-row
// stages (V via gload_lds; w = k_soft+m_soft reg-computed, LDS-written with 16B-granule
// XOR swizzle) and ONE atomic pass. The LAST block per (b,h) (device-scope counter)
// then computes W2T[b, :, h*64..h*64+64] from S (agent-scope loads for cross-XCD safety).

__global__ __launch_bounds__(256) void kv_fused(
    const ushort* __restrict__ QKV, const float* __restrict__ mk, float* __restrict__ S,
    const float* __restrict__ Wo, ushort* __restrict__ W2T, int* __restrict__ counters) {
  __shared__ ushort Vs[128 * 64];
  __shared__ ushort Ws[128 * 64];
  __shared__ int lastFlag;
  int bx = blockIdx.x;
  int bh = bx >> 4, nc = bx & 15;
  int b = bh >> 4, h = bh & 15;
  int t = threadIdx.x, w = t >> 6, l = t & 63;
  int d0 = (t & 15) * 4, e0 = (t >> 4) * 4;
  const int gq = d0 >> 3, sub = d0 & 7;   // logical granule + ushort offset within it
  float acc[4][4] = {};

  for (int c = 0; c < 2; ++c) {
    int row0 = b * 4096 + nc * 256 + c * 128;

    #pragma unroll
    for (int i = 0; i < 4; ++i) {
      int gb = w * 64 + i * 256, g = gb + l;
      int r = g >> 3, c16 = g & 7;
      gload_lds16(QKV + (size_t)(row0 + r) * 3072 + 2048 + h * 64 + c16 * 8, (void*)(Vs + gb * 8));
    }

    {
      int r = t >> 1, hf = t & 1;
      const uint4* kp = (const uint4*)(QKV + (size_t)(row0 + r) * 3072 + 1024 + h * 64 + hf * 32);
      float ke[32], me[32];
      #pragma unroll
      for (int i = 0; i < 4; ++i) unpack8(kp[i], SCALE, ke + i * 8);
      const float4* mp = (const float4*)(mk + (size_t)(row0 + r) * 1024 + h * 64 + hf * 32);
      #pragma unroll
      for (int i = 0; i < 8; ++i) {
        float4 f = mp[i];
        me[i*4+0] = f.x * SCALE; me[i*4+1] = f.y * SCALE;
        me[i*4+2] = f.z * SCALE; me[i*4+3] = f.w * SCALE;
      }
      float ksum = 0.f, msum = 0.f;
      #pragma unroll
      for (int i = 0; i < 32; ++i) { ke[i] = __expf(ke[i]); ksum += ke[i]; }
      #pragma unroll
      for (int i = 0; i < 32; ++i) { me[i] = __expf(me[i]); msum += me[i]; }
      ksum += __shfl_xor(ksum, 1);
      msum += __shfl_xor(msum, 1);
      float kinv = 1.f / ksum, minv = 1.f / msum;
      #pragma unroll
      for (int i = 0; i < 4; ++i) {
        int gsw = (hf * 4 + i) ^ (r & 7);   // granule swizzle (8x 16B granules/row)
        uint4 o = make_uint4(
          pack2bf(ke[i*8+0]*kinv + me[i*8+0]*minv, ke[i*8+1]*kinv + me[i*8+1]*minv),
          pack2bf(ke[i*8+2]*kinv + me[i*8+2]*minv, ke[i*8+3]*kinv + me[i*8+3]*minv),
          pack2bf(ke[i*8+4]*kinv + me[i*8+4]*minv, ke[i*8+5]*kinv + me[i*8+5]*minv),
          pack2bf(ke[i*8+6]*kinv + me[i*8+6]*minv, ke[i*8+7]*kinv + me[i*8+7]*minv));
        *(uint4*)(Ws + r * 64 + gsw * 8) = o;
      }
    }
    __syncthreads();

    #pragma unroll 4
    for (int n = 0; n < 128; ++n) {
      uint2 wp = *(const uint2*)(Ws + n * 64 + ((gq ^ (n & 7)) << 3) + sub);
      uint2 vp = *(const uint2*)(Vs + n * 64 + e0);
      float wd[4] = { bflo(wp.x), bfhi(wp.x), bflo(wp.y), bfhi(wp.y) };
      float vd[4] = { bflo(vp.x), bfhi(vp.x), bflo(vp.y), bfhi(vp.y) };
      #pragma unroll
      for (int i = 0; i < 4; ++i)
        #pragma unroll
        for (int j = 0; j < 4; ++j) acc[i][j] += wd[i] * vd[j];
    }
    __syncthreads();   // protect Vs/Ws before next chunk restages
  }

  float* Sp = S + (size_t)bh * 4096;
  #pragma unroll
  for (int i = 0; i < 4; ++i)
    #pragma unroll
    for (int j = 0; j < 4; ++j)
      atomicAdd(Sp + (d0 + i) * 64 + e0 + j, acc[i][j]);

  // ---- last-finisher tail: build W2T slice for this (b,h) ----
  __threadfence();                       // release: S atomics before counter bump
  if (t == 0) {
    int prev = atomicAdd(&counters[bh], 1);
    lastFlag = (prev == 15) ? 1 : 0;
  }
  __syncthreads();
  if (!lastFlag) return;
  __threadfence();                       // acquire side

  float* Sf = (float*)Vs;                // 16 KB stage of S[bh] (LDS free after barrier)
  #pragma unroll
  for (int i = 0; i < 16; ++i) {
    int idx = t + i * 256;
    Sf[idx] = __hip_atomic_load(Sp + idx, __ATOMIC_RELAXED, __HIP_MEMORY_SCOPE_AGENT);
  }
  __syncthreads();

  for (int ot = 0; ot < 4; ++ot) {
    int oo = ot * 256 + t;               // output column, coalesced across threads
    #pragma unroll
    for (int it = 0; it < 4; ++it) {
      float acc2[16];
      #pragma unroll
      for (int i = 0; i < 16; ++i) acc2[i] = 0.f;
      for (int e4 = 0; e4 < 16; ++e4) {  // 4 independent Wo loads in flight (MLP)
        float w0 = Wo[(size_t)(h*64 + e4*4 + 0) * 1024 + oo];
        float w1 = Wo[(size_t)(h*64 + e4*4 + 1) * 1024 + oo];
        float w2 = Wo[(size_t)(h*64 + e4*4 + 2) * 1024 + oo];
        float w3 = Wo[(size_t)(h*64 + e4*4 + 3) * 1024 + oo];
        #pragma unroll
        for (int i = 0; i < 16; ++i) {
          const float* sr = Sf + (it*16 + i) * 64 + e4*4;   // LDS broadcast reads
          acc2[i] += sr[0]*w0 + sr[1]*w1 + sr[2]*w2 + sr[3]*w3;
        }
      }
      ushort* dst = W2T + (size_t)(b * 1024 + oo) * 1024 + h * 64 + it * 16;
      #pragma unroll
      for (int i = 0; i < 16; ++i) dst[i] = f2bf(acc2[i]);
    }
  }
}

// ---------------- launch ----------------

extern "C" void kernel_launch(void* const* d_in, const int* in_sizes, int n_in,
                              void* d_out, int out_size, void* d_ws, size_t ws_size,
                              hipStream_t stream) {
  const float* x  = (const float*)d_in[0];
  const float* mk = (const float*)d_in[1];
  const float* Wq = (const float*)d_in[2];
  const float* bq = (const float*)d_in[3];
  const float* Wk = (const float*)d_in[4];
  const float* bk = (const float*)d_in[5];
  const float* Wv = (const float*)d_in[6];
  const float* bv = (const float*)d_in[7];
  const float* Wo = (const float*)d_in[8];
  const float* bo = (const float*)d_in[9];
  float* out = (float*)d_out;

  char* ws = (char*)d_ws;
  ushort* xb    = (ushort*)(ws);                    //  33,554,432
  ushort* wqkvT = (ushort*)(ws +  33554432);        //   6,291,456
  ushort* QKV   = (ushort*)(ws +  39845888);        // 100,663,296 (q third unused)
  ushort* qs    = (ushort*)(ws + 140509184);        //  33,554,432
  float*  S     = (float* )(ws + 207618048);        //   1,048,576
  ushort* W2T   = (ushort*)(ws + 208666624);        //   8,388,608
  int*    cnts  = (int*   )(ws + 217055232);        //         256

  cvt_all_kernel<<<5152, 256, 0, stream>>>((const float4*)x, (uint2*)xb,
                                           Wq, Wk, Wv, wqkvT, (float4*)S, cnts);
  gemm1_qkv<<<dim3(128, 24), 256, 0, stream>>>(xb, wqkvT, QKV, qs, bq, bk, bv);
  kv_fused<<<1024, 256, 0, stream>>>(QKV, mk, S, Wo, W2T, cnts);
  gemm2_out<<<dim3(128, 8), 256, 0, stream>>>(qs, W2T, out, bo);
}

// Round 16
// 311.558 us; speedup vs baseline: 1.8640x; 1.8640x over previous
//
#include <hip/hip_runtime.h>
#include <stdint.h>

typedef unsigned int uint;
typedef unsigned short ushort;
typedef __attribute__((ext_vector_type(4))) float  f32x4;
typedef __attribute__((ext_vector_type(8))) __bf16 bf16x8;

#define SCALE 0.125f   // 1/sqrt(64)

__device__ __forceinline__ ushort f2bf(float f) {
  uint u = __builtin_bit_cast(uint, f);
  u += 0x7FFFu + ((u >> 16) & 1u);
  return (ushort)(u >> 16);
}
__device__ __forceinline__ uint pack2bf(float a, float b) {
  return (uint)f2bf(a) | ((uint)f2bf(b) << 16);
}
__device__ __forceinline__ float bflo(uint u) { return __builtin_bit_cast(float, u << 16); }
__device__ __forceinline__ float bfhi(uint u) { return __builtin_bit_cast(float, u & 0xFFFF0000u); }

__device__ __forceinline__ void gload_lds16(const void* g, void* l) {
  __builtin_amdgcn_global_load_lds((const __attribute__((address_space(1))) void*)g,
                                   (__attribute__((address_space(3))) void*)l, 16, 0, 0);
}

__device__ __forceinline__ void unpack8(uint4 u, float s, float* x) {
  x[0]=bflo(u.x)*s; x[1]=bfhi(u.x)*s; x[2]=bflo(u.y)*s; x[3]=bfhi(u.y)*s;
  x[4]=bflo(u.z)*s; x[5]=bfhi(u.z)*s; x[6]=bflo(u.w)*s; x[7]=bfhi(u.w)*s;
}

// ---------------- fused conversions: x->bf16, Wqkv->transposed bf16, S zero ----------------

__global__ __launch_bounds__(256) void cvt_all_kernel(
    const float4* __restrict__ x, uint2* __restrict__ xb,
    const float* __restrict__ Wq, const float* __restrict__ Wk, const float* __restrict__ Wv,
    ushort* __restrict__ WT, float4* __restrict__ S4) {
  __shared__ float tile[32][33];
  int bx = blockIdx.x;
  if (bx < 2048) {
    int i = bx * 256 + threadIdx.x;   // 524288 threads
    #pragma unroll
    for (int k = 0; k < 8; ++k) {
      int idx = i + k * 524288;       // total 4194304 float4s
      float4 f = x[idx];
      xb[idx] = make_uint2(pack2bf(f.x, f.y), pack2bf(f.z, f.w));
    }
  } else if (bx < 5120) {
    int lin = bx - 2048;              // 0..3071
    int mat = lin >> 10;
    int rem = lin & 1023;
    int cb = rem & 31, rb = rem >> 5;
    const float* W = (mat == 0) ? Wq : (mat == 1) ? Wk : Wv;
    int tx = threadIdx.x & 31, ty = threadIdx.x >> 5;
    int c0 = cb * 32, r0 = rb * 32;
    #pragma unroll
    for (int i = 0; i < 4; ++i)
      tile[ty + i*8][tx] = W[(size_t)(r0 + ty + i*8) * 1024 + c0 + tx];
    __syncthreads();
    #pragma unroll
    for (int i = 0; i < 4; ++i)
      WT[(size_t)(mat*1024 + c0 + ty + i*8) * 1024 + r0 + tx] = f2bf(tile[tx][ty + i*8]);
  } else {
    // zero S: 64*4096 floats = 65536 float4s; 32 blocks x 256 threads x 8
    int base = ((bx - 5120) * 256 + threadIdx.x) * 8;
    const float4 z = {0.f, 0.f, 0.f, 0.f};
    #pragma unroll
    for (int j = 0; j < 8; ++j) S4[base + j] = z;
  }
}

// ---------------- GEMM1: QKV = xb @ WqkvT^T, fused q-softmax epilogue ----------------
// 128x128 tile, m97 structure. Grid dim3(128, 24): x=m-tile (XCD partition axis).
// n0<1024: q path -> softmax(acc+bq) -> qs (bf16). Else: k/v -> QKV + bias (bf16).

__global__ __launch_bounds__(256, 2) void gemm1_qkv(
    const ushort* __restrict__ A, const ushort* __restrict__ B,
    ushort* __restrict__ QKV, ushort* __restrict__ qs,
    const float* __restrict__ bq, const float* __restrict__ bk, const float* __restrict__ bv) {
  __shared__ ushort As[128 * 64];
  __shared__ ushort Bs[128 * 64];
  const int K = 1024;
  const int t = threadIdx.x;
  const int w = t >> 6, l = t & 63;
  const int wr = w >> 1, wc = w & 1;
  const int m0 = blockIdx.x * 128;
  const int n0 = blockIdx.y * 128;
  const ushort* Ap = A + (size_t)m0 * K;
  const ushort* Bp = B + (size_t)n0 * K;

  f32x4 acc[4][4];
  const f32x4 zf = {0.f, 0.f, 0.f, 0.f};
  #pragma unroll
  for (int i = 0; i < 4; ++i)
    #pragma unroll
    for (int j = 0; j < 4; ++j) acc[i][j] = zf;

  const int lr = l & 15, lg = l >> 4;

  for (int kt = 0; kt < K; kt += 64) {
    #pragma unroll
    for (int i = 0; i < 4; ++i) {
      int gb = w * 64 + i * 256;
      int g  = gb + l;
      int row = g >> 3, c16 = g & 7;
      gload_lds16(Ap + (size_t)row * K + kt + c16 * 8, (void*)(As + gb * 8));
      gload_lds16(Bp + (size_t)row * K + kt + c16 * 8, (void*)(Bs + gb * 8));
    }
    __syncthreads();
    #pragma unroll
    for (int kk = 0; kk < 64; kk += 32) {
      bf16x8 a[4], b[4];
      #pragma unroll
      for (int m = 0; m < 4; ++m)
        a[m] = *(const bf16x8*)(As + (wr*64 + m*16 + lr) * 64 + kk + lg * 8);
      #pragma unroll
      for (int n = 0; n < 4; ++n)
        b[n] = *(const bf16x8*)(Bs + (wc*64 + n*16 + lr) * 64 + kk + lg * 8);
      #pragma unroll
      for (int m = 0; m < 4; ++m)
        #pragma unroll
        for (int n = 0; n < 4; ++n)
          acc[m][n] = __builtin_amdgcn_mfma_f32_16x16x32_bf16(a[m], b[n], acc[m][n], 0, 0, 0);
    }
    __syncthreads();
  }

  // C/D mapping: col=lane&15, row=(lane>>4)*4+j (m89)
  if (n0 < 1024) {
    // q path: softmax over the wave's 64-col head chunk (4 regs x 16 lr lanes)
    const int cb = n0 + wc * 64;
    float bvv[4];
    #pragma unroll
    for (int n = 0; n < 4; ++n) bvv[n] = bq[cb + n*16 + lr];
    #pragma unroll
    for (int m = 0; m < 4; ++m) {
      #pragma unroll
      for (int j = 0; j < 4; ++j) {
        int row = m0 + wr*64 + m*16 + lg*4 + j;
        float v[4];
        float s = 0.f;
        #pragma unroll
        for (int n = 0; n < 4; ++n) {
          v[n] = __expf((acc[m][n][j] + bvv[n]) * SCALE);
          s += v[n];
        }
        s += __shfl_xor(s, 1);
        s += __shfl_xor(s, 2);
        s += __shfl_xor(s, 4);
        s += __shfl_xor(s, 8);
        float inv = 1.f / s;
        #pragma unroll
        for (int n = 0; n < 4; ++n)
          qs[(size_t)row * 1024 + cb + n*16 + lr] = f2bf(v[n] * inv);
      }
    }
  } else {
    const float* bp = (n0 < 2048) ? bk : bv;
    #pragma unroll
    for (int n = 0; n < 4; ++n) {
      int col = n0 + wc*64 + n*16 + lr;
      float bvv = bp[col & 1023];
      #pragma unroll
      for (int m = 0; m < 4; ++m) {
        #pragma unroll
        for (int j = 0; j < 4; ++j) {
          int row = m0 + wr*64 + m*16 + lg*4 + j;
          QKV[(size_t)row * 3072 + col] = f2bf(acc[m][n][j] + bvv);
        }
      }
    }
  }
}

// ---------------- GEMM2: out = qs @ W2T^T + bo (f32 out) ----------------

__global__ __launch_bounds__(256, 2) void gemm2_out(
    const ushort* __restrict__ A, const ushort* __restrict__ B, float* __restrict__ C,
    const float* __restrict__ bo) {
  __shared__ ushort As[128 * 64];
  __shared__ ushort Bs[128 * 64];
  const int K = 1024;
  const int t = threadIdx.x;
  const int w = t >> 6, l = t & 63;
  const int wr = w >> 1, wc = w & 1;
  const int m0 = blockIdx.x * 128;
  const int n0 = blockIdx.y * 128;
  const ushort* Ap = A + (size_t)m0 * K;
  const ushort* Bp = B + (size_t)(m0 >> 12) * (1024 * 1024) + (size_t)n0 * K;

  f32x4 acc[4][4];
  const f32x4 zf = {0.f, 0.f, 0.f, 0.f};
  #pragma unroll
  for (int i = 0; i < 4; ++i)
    #pragma unroll
    for (int j = 0; j < 4; ++j) acc[i][j] = zf;

  const int lr = l & 15, lg = l >> 4;

  for (int kt = 0; kt < K; kt += 64) {
    #pragma unroll
    for (int i = 0; i < 4; ++i) {
      int gb = w * 64 + i * 256;
      int g  = gb + l;
      int row = g >> 3, c16 = g & 7;
      gload_lds16(Ap + (size_t)row * K + kt + c16 * 8, (void*)(As + gb * 8));
      gload_lds16(Bp + (size_t)row * K + kt + c16 * 8, (void*)(Bs + gb * 8));
    }
    __syncthreads();
    #pragma unroll
    for (int kk = 0; kk < 64; kk += 32) {
      bf16x8 a[4], b[4];
      #pragma unroll
      for (int m = 0; m < 4; ++m)
        a[m] = *(const bf16x8*)(As + (wr*64 + m*16 + lr) * 64 + kk + lg * 8);
      #pragma unroll
      for (int n = 0; n < 4; ++n)
        b[n] = *(const bf16x8*)(Bs + (wc*64 + n*16 + lr) * 64 + kk + lg * 8);
      #pragma unroll
      for (int m = 0; m < 4; ++m)
        #pragma unroll
        for (int n = 0; n < 4; ++n)
          acc[m][n] = __builtin_amdgcn_mfma_f32_16x16x32_bf16(a[m], b[n], acc[m][n], 0, 0, 0);
    }
    __syncthreads();
  }

  #pragma unroll
  for (int n = 0; n < 4; ++n) {
    int col = n0 + wc*64 + n*16 + lr;
    float bvv = bo[col];
    #pragma unroll
    for (int m = 0; m < 4; ++m) {
      #pragma unroll
      for (int j = 0; j < 4; ++j) {
        int row = m0 + wr*64 + m*16 + lg*4 + j;
        C[(size_t)row * 1024 + col] = acc[m][n][j] + bvv;
      }
    }
  }
}

// ---------------- fused: softmax(k)+softmax(mk), then S += w^T v ----------------
// 1024 blocks = (b,h) x 16 chunks of 256 rows; each block does 2 sequential 128-row
// stages (V via gload_lds; w = k_soft+m_soft reg-computed, LDS-written with 16B-granule
// XOR swizzle) and ONE atomic pass at the end.

__global__ __launch_bounds__(256) void kv_fused(
    const ushort* __restrict__ QKV, const float* __restrict__ mk, float* __restrict__ S) {
  __shared__ ushort Vs[128 * 64];
  __shared__ ushort Ws[128 * 64];
  int bx = blockIdx.x;
  int bh = bx >> 4, nc = bx & 15;
  int b = bh >> 4, h = bh & 15;
  int t = threadIdx.x, w = t >> 6, l = t & 63;
  int d0 = (t & 15) * 4, e0 = (t >> 4) * 4;
  const int gq = d0 >> 3, sub = d0 & 7;   // logical granule + ushort offset within it
  float acc[4][4] = {};

  for (int c = 0; c < 2; ++c) {
    int row0 = b * 4096 + nc * 256 + c * 128;

    #pragma unroll
    for (int i = 0; i < 4; ++i) {
      int gb = w * 64 + i * 256, g = gb + l;
      int r = g >> 3, c16 = g & 7;
      gload_lds16(QKV + (size_t)(row0 + r) * 3072 + 2048 + h * 64 + c16 * 8, (void*)(Vs + gb * 8));
    }

    {
      int r = t >> 1, hf = t & 1;
      const uint4* kp = (const uint4*)(QKV + (size_t)(row0 + r) * 3072 + 1024 + h * 64 + hf * 32);
      float ke[32], me[32];
      #pragma unroll
      for (int i = 0; i < 4; ++i) unpack8(kp[i], SCALE, ke + i * 8);
      const float4* mp = (const float4*)(mk + (size_t)(row0 + r) * 1024 + h * 64 + hf * 32);
      #pragma unroll
      for (int i = 0; i < 8; ++i) {
        float4 f = mp[i];
        me[i*4+0] = f.x * SCALE; me[i*4+1] = f.y * SCALE;
        me[i*4+2] = f.z * SCALE; me[i*4+3] = f.w * SCALE;
      }
      float ksum = 0.f, msum = 0.f;
      #pragma unroll
      for (int i = 0; i < 32; ++i) { ke[i] = __expf(ke[i]); ksum += ke[i]; }
      #pragma unroll
      for (int i = 0; i < 32; ++i) { me[i] = __expf(me[i]); msum += me[i]; }
      ksum += __shfl_xor(ksum, 1);
      msum += __shfl_xor(msum, 1);
      float kinv = 1.f / ksum, minv = 1.f / msum;
      #pragma unroll
      for (int i = 0; i < 4; ++i) {
        int gsw = (hf * 4 + i) ^ (r & 7);   // granule swizzle (8x 16B granules/row)
        uint4 o = make_uint4(
          pack2bf(ke[i*8+0]*kinv + me[i*8+0]*minv, ke[i*8+1]*kinv + me[i*8+1]*minv),
          pack2bf(ke[i*8+2]*kinv + me[i*8+2]*minv, ke[i*8+3]*kinv + me[i*8+3]*minv),
          pack2bf(ke[i*8+4]*kinv + me[i*8+4]*minv, ke[i*8+5]*kinv + me[i*8+5]*minv),
          pack2bf(ke[i*8+6]*kinv + me[i*8+6]*minv, ke[i*8+7]*kinv + me[i*8+7]*minv));
        *(uint4*)(Ws + r * 64 + gsw * 8) = o;
      }
    }
    __syncthreads();

    #pragma unroll 4
    for (int n = 0; n < 128; ++n) {
      uint2 wp = *(const uint2*)(Ws + n * 64 + ((gq ^ (n & 7)) << 3) + sub);
      uint2 vp = *(const uint2*)(Vs + n * 64 + e0);
      float wd[4] = { bflo(wp.x), bfhi(wp.x), bflo(wp.y), bfhi(wp.y) };
      float vd[4] = { bflo(vp.x), bfhi(vp.x), bflo(vp.y), bfhi(vp.y) };
      #pragma unroll
      for (int i = 0; i < 4; ++i)
        #pragma unroll
        for (int j = 0; j < 4; ++j) acc[i][j] += wd[i] * vd[j];
    }
    __syncthreads();   // protect Vs/Ws before next chunk restages
  }

  float* Sp = S + (size_t)bh * 4096;
  #pragma unroll
  for (int i = 0; i < 4; ++i)
    #pragma unroll
    for (int j = 0; j < 4; ++j)
      atomicAdd(Sp + (d0 + i) * 64 + e0 + j, acc[i][j]);
}

// ---------------- W2T[b][o][i] = sum_e S[b,h(i)][i%64][e] * Wo[h*64+e][o]  (bf16, BT layout) ----

__global__ __launch_bounds__(256) void make_w2t(
    const float* __restrict__ S, const float* __restrict__ Wo, ushort* __restrict__ W2T) {
  int bx = blockIdx.x;            // 1024 = b(4) h(16) ot(4) it(4)
  int b = bx >> 8, h = (bx >> 4) & 15, ot = (bx >> 2) & 3, it = bx & 3;
  int t = threadIdx.x;
  __shared__ float Ss[16 * 64];
  const float* Sp = S + (size_t)(b * 16 + h) * 4096 + it * 1024;
  #pragma unroll
  for (int i = 0; i < 4; ++i) Ss[t + i * 256] = Sp[t + i * 256];
  __syncthreads();
  int o = ot * 256 + t;
  float acc[16] = {};
  for (int e = 0; e < 64; ++e) {
    float wo = Wo[(size_t)(h * 64 + e) * 1024 + o];
    #pragma unroll
    for (int i = 0; i < 16; ++i) acc[i] += Ss[i * 64 + e] * wo;
  }
  ushort* dst = W2T + (size_t)(b * 1024 + o) * 1024 + h * 64 + it * 16;
  #pragma unroll
  for (int i = 0; i < 16; ++i) dst[i] = f2bf(acc[i]);
}

// ---------------- launch ----------------

extern "C" void kernel_launch(void* const* d_in, const int* in_sizes, int n_in,
                              void* d_out, int out_size, void* d_ws, size_t ws_size,
                              hipStream_t stream) {
  const float* x  = (const float*)d_in[0];
  const float* mk = (const float*)d_in[1];
  const float* Wq = (const float*)d_in[2];
  const float* bq = (const float*)d_in[3];
  const float* Wk = (const float*)d_in[4];
  const float* bk = (const float*)d_in[5];
  const float* Wv = (const float*)d_in[6];
  const float* bv = (const float*)d_in[7];
  const float* Wo = (const float*)d_in[8];
  const float* bo = (const float*)d_in[9];
  float* out = (float*)d_out;

  char* ws = (char*)d_ws;
  ushort* xb    = (ushort*)(ws);                    //  33,554,432
  ushort* wqkvT = (ushort*)(ws +  33554432);        //   6,291,456
  ushort* QKV   = (ushort*)(ws +  39845888);        // 100,663,296 (q third unused)
  ushort* qs    = (ushort*)(ws + 140509184);        //  33,554,432
  float*  S     = (float* )(ws + 207618048);        //   1,048,576
  ushort* W2T   = (ushort*)(ws + 208666624);        //   8,388,608

  cvt_all_kernel<<<5152, 256, 0, stream>>>((const float4*)x, (uint2*)xb,
                                           Wq, Wk, Wv, wqkvT, (float4*)S);
  gemm1_qkv<<<dim3(128, 24), 256, 0, stream>>>(xb, wqkvT, QKV, qs, bq, bk, bv);
  kv_fused<<<1024, 256, 0, stream>>>(QKV, mk, S);
  make_w2t<<<1024, 256, 0, stream>>>(S, Wo, W2T);
  gemm2_out<<<dim3(128, 8), 256, 0, stream>>>(qs, W2T, out, bo);
}

// Round 17
// 297.339 us; speedup vs baseline: 1.9531x; 1.0478x over previous
//
#include <hip/hip_runtime.h>
#include <stdint.h>

typedef unsigned int uint;
typedef unsigned short ushort;
typedef __attribute__((ext_vector_type(4))) float  f32x4;
typedef __attribute__((ext_vector_type(8))) __bf16 bf16x8;

#define SCALE 0.125f   // 1/sqrt(64)

__device__ __forceinline__ ushort f2bf(float f) {
  uint u = __builtin_bit_cast(uint, f);
  u += 0x7FFFu + ((u >> 16) & 1u);
  return (ushort)(u >> 16);
}
__device__ __forceinline__ uint pack2bf(float a, float b) {
  return (uint)f2bf(a) | ((uint)f2bf(b) << 16);
}
__device__ __forceinline__ float bflo(uint u) { return __builtin_bit_cast(float, u << 16); }
__device__ __forceinline__ float bfhi(uint u) { return __builtin_bit_cast(float, u & 0xFFFF0000u); }

__device__ __forceinline__ void gload_lds16(const void* g, void* l) {
  __builtin_amdgcn_global_load_lds((const __attribute__((address_space(1))) void*)g,
                                   (__attribute__((address_space(3))) void*)l, 16, 0, 0);
}

__device__ __forceinline__ void unpack8(uint4 u, float s, float* x) {
  x[0]=bflo(u.x)*s; x[1]=bfhi(u.x)*s; x[2]=bflo(u.y)*s; x[3]=bfhi(u.y)*s;
  x[4]=bflo(u.z)*s; x[5]=bfhi(u.z)*s; x[6]=bflo(u.w)*s; x[7]=bfhi(u.w)*s;
}

// ---------------- fused conversions: x->bf16, Wqkv->transposed bf16, S zero ----------------

__global__ __launch_bounds__(256) void cvt_all_kernel(
    const float4* __restrict__ x, uint2* __restrict__ xb,
    const float* __restrict__ Wq, const float* __restrict__ Wk, const float* __restrict__ Wv,
    ushort* __restrict__ WT, float4* __restrict__ S4) {
  __shared__ float tile[32][33];
  int bx = blockIdx.x;
  if (bx < 2048) {
    int i = bx * 256 + threadIdx.x;   // 524288 threads
    #pragma unroll
    for (int k = 0; k < 8; ++k) {
      int idx = i + k * 524288;       // total 4194304 float4s
      float4 f = x[idx];
      xb[idx] = make_uint2(pack2bf(f.x, f.y), pack2bf(f.z, f.w));
    }
  } else if (bx < 5120) {
    int lin = bx - 2048;              // 0..3071
    int mat = lin >> 10;
    int rem = lin & 1023;
    int cb = rem & 31, rb = rem >> 5;
    const float* W = (mat == 0) ? Wq : (mat == 1) ? Wk : Wv;
    int tx = threadIdx.x & 31, ty = threadIdx.x >> 5;
    int c0 = cb * 32, r0 = rb * 32;
    #pragma unroll
    for (int i = 0; i < 4; ++i)
      tile[ty + i*8][tx] = W[(size_t)(r0 + ty + i*8) * 1024 + c0 + tx];
    __syncthreads();
    #pragma unroll
    for (int i = 0; i < 4; ++i)
      WT[(size_t)(mat*1024 + c0 + ty + i*8) * 1024 + r0 + tx] = f2bf(tile[tx][ty + i*8]);
  } else {
    // zero S: 64*4096 floats = 65536 float4s; 32 blocks x 256 threads x 8
    int base = ((bx - 5120) * 256 + threadIdx.x) * 8;
    const float4 z = {0.f, 0.f, 0.f, 0.f};
    #pragma unroll
    for (int j = 0; j < 8; ++j) S4[base + j] = z;
  }
}

// ---------------- GEMM1: QKV = xb @ WqkvT^T, fused q-softmax epilogue ----------------
// 128x128 tile, m97 structure. Grid dim3(128, 24): x=m-tile (XCD partition axis).
// __launch_bounds__(256, 4): force arch-VGPR <= 64 so VGPR(64)+AGPR(64) = 128/wave
// -> 4 waves/SIMD (was 76+64=140 -> 3), doubling resident blocks to hide the
// pre-barrier vmcnt drain (the m97 structure's known stall).

__global__ __launch_bounds__(256, 4) void gemm1_qkv(
    const ushort* __restrict__ A, const ushort* __restrict__ B,
    ushort* __restrict__ QKV, ushort* __restrict__ qs,
    const float* __restrict__ bq, const float* __restrict__ bk, const float* __restrict__ bv) {
  __shared__ ushort As[128 * 64];
  __shared__ ushort Bs[128 * 64];
  const int K = 1024;
  const int t = threadIdx.x;
  const int w = t >> 6, l = t & 63;
  const int wr = w >> 1, wc = w & 1;
  const int m0 = blockIdx.x * 128;
  const int n0 = blockIdx.y * 128;
  const ushort* Ap = A + (size_t)m0 * K;
  const ushort* Bp = B + (size_t)n0 * K;

  f32x4 acc[4][4];
  const f32x4 zf = {0.f, 0.f, 0.f, 0.f};
  #pragma unroll
  for (int i = 0; i < 4; ++i)
    #pragma unroll
    for (int j = 0; j < 4; ++j) acc[i][j] = zf;

  const int lr = l & 15, lg = l >> 4;

  for (int kt = 0; kt < K; kt += 64) {
    #pragma unroll
    for (int i = 0; i < 4; ++i) {
      int gb = w * 64 + i * 256;
      int g  = gb + l;
      int row = g >> 3, c16 = g & 7;
      gload_lds16(Ap + (size_t)row * K + kt + c16 * 8, (void*)(As + gb * 8));
      gload_lds16(Bp + (size_t)row * K + kt + c16 * 8, (void*)(Bs + gb * 8));
    }
    __syncthreads();
    #pragma unroll
    for (int kk = 0; kk < 64; kk += 32) {
      bf16x8 a[4], b[4];
      #pragma unroll
      for (int m = 0; m < 4; ++m)
        a[m] = *(const bf16x8*)(As + (wr*64 + m*16 + lr) * 64 + kk + lg * 8);
      #pragma unroll
      for (int n = 0; n < 4; ++n)
        b[n] = *(const bf16x8*)(Bs + (wc*64 + n*16 + lr) * 64 + kk + lg * 8);
      #pragma unroll
      for (int m = 0; m < 4; ++m)
        #pragma unroll
        for (int n = 0; n < 4; ++n)
          acc[m][n] = __builtin_amdgcn_mfma_f32_16x16x32_bf16(a[m], b[n], acc[m][n], 0, 0, 0);
    }
    __syncthreads();
  }

  // C/D mapping: col=lane&15, row=(lane>>4)*4+j (m89)
  if (n0 < 1024) {
    // q path: softmax over the wave's 64-col head chunk (4 regs x 16 lr lanes)
    const int cb = n0 + wc * 64;
    float bvv[4];
    #pragma unroll
    for (int n = 0; n < 4; ++n) bvv[n] = bq[cb + n*16 + lr];
    #pragma unroll
    for (int m = 0; m < 4; ++m) {
      #pragma unroll
      for (int j = 0; j < 4; ++j) {
        int row = m0 + wr*64 + m*16 + lg*4 + j;
        float v[4];
        float s = 0.f;
        #pragma unroll
        for (int n = 0; n < 4; ++n) {
          v[n] = __expf((acc[m][n][j] + bvv[n]) * SCALE);
          s += v[n];
        }
        s += __shfl_xor(s, 1);
        s += __shfl_xor(s, 2);
        s += __shfl_xor(s, 4);
        s += __shfl_xor(s, 8);
        float inv = 1.f / s;
        #pragma unroll
        for (int n = 0; n < 4; ++n)
          qs[(size_t)row * 1024 + cb + n*16 + lr] = f2bf(v[n] * inv);
      }
    }
  } else {
    const float* bp = (n0 < 2048) ? bk : bv;
    #pragma unroll
    for (int n = 0; n < 4; ++n) {
      int col = n0 + wc*64 + n*16 + lr;
      float bvv = bp[col & 1023];
      #pragma unroll
      for (int m = 0; m < 4; ++m) {
        #pragma unroll
        for (int j = 0; j < 4; ++j) {
          int row = m0 + wr*64 + m*16 + lg*4 + j;
          QKV[(size_t)row * 3072 + col] = f2bf(acc[m][n][j] + bvv);
        }
      }
    }
  }
}

// ---------------- GEMM2: out = qs @ W2T^T + bo (f32 out) ----------------

__global__ __launch_bounds__(256, 4) void gemm2_out(
    const ushort* __restrict__ A, const ushort* __restrict__ B, float* __restrict__ C,
    const float* __restrict__ bo) {
  __shared__ ushort As[128 * 64];
  __shared__ ushort Bs[128 * 64];
  const int K = 1024;
  const int t = threadIdx.x;
  const int w = t >> 6, l = t & 63;
  const int wr = w >> 1, wc = w & 1;
  const int m0 = blockIdx.x * 128;
  const int n0 = blockIdx.y * 128;
  const ushort* Ap = A + (size_t)m0 * K;
  const ushort* Bp = B + (size_t)(m0 >> 12) * (1024 * 1024) + (size_t)n0 * K;

  f32x4 acc[4][4];
  const f32x4 zf = {0.f, 0.f, 0.f, 0.f};
  #pragma unroll
  for (int i = 0; i < 4; ++i)
    #pragma unroll
    for (int j = 0; j < 4; ++j) acc[i][j] = zf;

  const int lr = l & 15, lg = l >> 4;

  for (int kt = 0; kt < K; kt += 64) {
    #pragma unroll
    for (int i = 0; i < 4; ++i) {
      int gb = w * 64 + i * 256;
      int g  = gb + l;
      int row = g >> 3, c16 = g & 7;
      gload_lds16(Ap + (size_t)row * K + kt + c16 * 8, (void*)(As + gb * 8));
      gload_lds16(Bp + (size_t)row * K + kt + c16 * 8, (void*)(Bs + gb * 8));
    }
    __syncthreads();
    #pragma unroll
    for (int kk = 0; kk < 64; kk += 32) {
      bf16x8 a[4], b[4];
      #pragma unroll
      for (int m = 0; m < 4; ++m)
        a[m] = *(const bf16x8*)(As + (wr*64 + m*16 + lr) * 64 + kk + lg * 8);
      #pragma unroll
      for (int n = 0; n < 4; ++n)
        b[n] = *(const bf16x8*)(Bs + (wc*64 + n*16 + lr) * 64 + kk + lg * 8);
      #pragma unroll
      for (int m = 0; m < 4; ++m)
        #pragma unroll
        for (int n = 0; n < 4; ++n)
          acc[m][n] = __builtin_amdgcn_mfma_f32_16x16x32_bf16(a[m], b[n], acc[m][n], 0, 0, 0);
    }
    __syncthreads();
  }

  #pragma unroll
  for (int n = 0; n < 4; ++n) {
    int col = n0 + wc*64 + n*16 + lr;
    float bvv = bo[col];
    #pragma unroll
    for (int m = 0; m < 4; ++m) {
      #pragma unroll
      for (int j = 0; j < 4; ++j) {
        int row = m0 + wr*64 + m*16 + lg*4 + j;
        C[(size_t)row * 1024 + col] = acc[m][n][j] + bvv;
      }
    }
  }
}

// ---------------- fused: softmax(k)+softmax(mk), then S += w^T v ----------------
// 1024 blocks = (b,h) x 16 chunks of 256 rows; each block does 2 sequential 128-row
// stages (V via gload_lds; w = k_soft+m_soft reg-computed, LDS-written with 16B-granule
// XOR swizzle) and ONE atomic pass at the end.

__global__ __launch_bounds__(256) void kv_fused(
    const ushort* __restrict__ QKV, const float* __restrict__ mk, float* __restrict__ S) {
  __shared__ ushort Vs[128 * 64];
  __shared__ ushort Ws[128 * 64];
  int bx = blockIdx.x;
  int bh = bx >> 4, nc = bx & 15;
  int b = bh >> 4, h = bh & 15;
  int t = threadIdx.x, w = t >> 6, l = t & 63;
  int d0 = (t & 15) * 4, e0 = (t >> 4) * 4;
  const int gq = d0 >> 3, sub = d0 & 7;   // logical granule + ushort offset within it
  float acc[4][4] = {};

  for (int c = 0; c < 2; ++c) {
    int row0 = b * 4096 + nc * 256 + c * 128;

    #pragma unroll
    for (int i = 0; i < 4; ++i) {
      int gb = w * 64 + i * 256, g = gb + l;
      int r = g >> 3, c16 = g & 7;
      gload_lds16(QKV + (size_t)(row0 + r) * 3072 + 2048 + h * 64 + c16 * 8, (void*)(Vs + gb * 8));
    }

    {
      int r = t >> 1, hf = t & 1;
      const uint4* kp = (const uint4*)(QKV + (size_t)(row0 + r) * 3072 + 1024 + h * 64 + hf * 32);
      float ke[32], me[32];
      #pragma unroll
      for (int i = 0; i < 4; ++i) unpack8(kp[i], SCALE, ke + i * 8);
      const float4* mp = (const float4*)(mk + (size_t)(row0 + r) * 1024 + h * 64 + hf * 32);
      #pragma unroll
      for (int i = 0; i < 8; ++i) {
        float4 f = mp[i];
        me[i*4+0] = f.x * SCALE; me[i*4+1] = f.y * SCALE;
        me[i*4+2] = f.z * SCALE; me[i*4+3] = f.w * SCALE;
      }
      float ksum = 0.f, msum = 0.f;
      #pragma unroll
      for (int i = 0; i < 32; ++i) { ke[i] = __expf(ke[i]); ksum += ke[i]; }
      #pragma unroll
      for (int i = 0; i < 32; ++i) { me[i] = __expf(me[i]); msum += me[i]; }
      ksum += __shfl_xor(ksum, 1);
      msum += __shfl_xor(msum, 1);
      float kinv = 1.f / ksum, minv = 1.f / msum;
      #pragma unroll
      for (int i = 0; i < 4; ++i) {
        int gsw = (hf * 4 + i) ^ (r & 7);   // granule swizzle (8x 16B granules/row)
        uint4 o = make_uint4(
          pack2bf(ke[i*8+0]*kinv + me[i*8+0]*minv, ke[i*8+1]*kinv + me[i*8+1]*minv),
          pack2bf(ke[i*8+2]*kinv + me[i*8+2]*minv, ke[i*8+3]*kinv + me[i*8+3]*minv),
          pack2bf(ke[i*8+4]*kinv + me[i*8+4]*minv, ke[i*8+5]*kinv + me[i*8+5]*minv),
          pack2bf(ke[i*8+6]*kinv + me[i*8+6]*minv, ke[i*8+7]*kinv + me[i*8+7]*minv));
        *(uint4*)(Ws + r * 64 + gsw * 8) = o;
      }
    }
    __syncthreads();

    #pragma unroll 4
    for (int n = 0; n < 128; ++n) {
      uint2 wp = *(const uint2*)(Ws + n * 64 + ((gq ^ (n & 7)) << 3) + sub);
      uint2 vp = *(const uint2*)(Vs + n * 64 + e0);
      float wd[4] = { bflo(wp.x), bfhi(wp.x), bflo(wp.y), bfhi(wp.y) };
      float vd[4] = { bflo(vp.x), bfhi(vp.x), bflo(vp.y), bfhi(vp.y) };
      #pragma unroll
      for (int i = 0; i < 4; ++i)
        #pragma unroll
        for (int j = 0; j < 4; ++j) acc[i][j] += wd[i] * vd[j];
    }
    __syncthreads();   // protect Vs/Ws before next chunk restages
  }

  float* Sp = S + (size_t)bh * 4096;
  #pragma unroll
  for (int i = 0; i < 4; ++i)
    #pragma unroll
    for (int j = 0; j < 4; ++j)
      atomicAdd(Sp + (d0 + i) * 64 + e0 + j, acc[i][j]);
}

// ---------------- W2T[b][o][i] = sum_e S[b,h(i)][i%64][e] * Wo[h*64+e][o]  (bf16, BT layout) ----

__global__ __launch_bounds__(256) void make_w2t(
    const float* __restrict__ S, const float* __restrict__ Wo, ushort* __restrict__ W2T) {
  int bx = blockIdx.x;            // 1024 = b(4) h(16) ot(4) it(4)
  int b = bx >> 8, h = (bx >> 4) & 15, ot = (bx >> 2) & 3, it = bx & 3;
  int t = threadIdx.x;
  __shared__ float Ss[16 * 64];
  const float* Sp = S + (size_t)(b * 16 + h) * 4096 + it * 1024;
  #pragma unroll
  for (int i = 0; i < 4; ++i) Ss[t + i * 256] = Sp[t + i * 256];
  __syncthreads();
  int o = ot * 256 + t;
  float acc[16] = {};
  for (int e = 0; e < 64; ++e) {
    float wo = Wo[(size_t)(h * 64 + e) * 1024 + o];
    #pragma unroll
    for (int i = 0; i < 16; ++i) acc[i] += Ss[i * 64 + e] * wo;
  }
  ushort* dst = W2T + (size_t)(b * 1024 + o) * 1024 + h * 64 + it * 16;
  #pragma unroll
  for (int i = 0; i < 16; ++i) dst[i] = f2bf(acc[i]);
}

// ---------------- launch ----------------

extern "C" void kernel_launch(void* const* d_in, const int* in_sizes, int n_in,
                              void* d_out, int out_size, void* d_ws, size_t ws_size,
                              hipStream_t stream) {
  const float* x  = (const float*)d_in[0];
  const float* mk = (const float*)d_in[1];
  const float* Wq = (const float*)d_in[2];
  const float* bq = (const float*)d_in[3];
  const float* Wk = (const float*)d_in[4];
  const float* bk = (const float*)d_in[5];
  const float* Wv = (const float*)d_in[6];
  const float* bv = (const float*)d_in[7];
  const float* Wo = (const float*)d_in[8];
  const float* bo = (const float*)d_in[9];
  float* out = (float*)d_out;

  char* ws = (char*)d_ws;
  ushort* xb    = (ushort*)(ws);                    //  33,554,432
  ushort* wqkvT = (ushort*)(ws +  33554432);        //   6,291,456
  ushort* QKV   = (ushort*)(ws +  39845888);        // 100,663,296 (q third unused)
  ushort* qs    = (ushort*)(ws + 140509184);        //  33,554,432
  float*  S     = (float* )(ws + 207618048);        //   1,048,576
  ushort* W2T   = (ushort*)(ws + 208666624);        //   8,388,608

  cvt_all_kernel<<<5152, 256, 0, stream>>>((const float4*)x, (uint2*)xb,
                                           Wq, Wk, Wv, wqkvT, (float4*)S);
  gemm1_qkv<<<dim3(128, 24), 256, 0, stream>>>(xb, wqkvT, QKV, qs, bq, bk, bv);
  kv_fused<<<1024, 256, 0, stream>>>(QKV, mk, S);
  make_w2t<<<1024, 256, 0, stream>>>(S, Wo, W2T);
  gemm2_out<<<dim3(128, 8), 256, 0, stream>>>(qs, W2T, out, bo);
}